// Round 1
// baseline (269.893 us; speedup 1.0000x reference)
//
#include <hip/hip_runtime.h>
#include <math.h>

// EnvironmentLight: per-point IBL shade.
// Inputs (float32): view_dir(N,3) normal(N,3) kd(N,3) ks(N,3) reflect_occ(N,1)
//   diffuse_map(6,16,16,3) spec0..5 (6,R,R,3) R=512>>lvl  fg_lut(256,256,2)
// Output: (N,3) float32 sRGB.

__device__ __forceinline__ void cube_face_uv(float x, float y, float z,
                                             int& face, float& uo, float& vo) {
    float ax = fabsf(x), ay = fabsf(y), az = fabsf(z);
    bool is_x = (ax >= ay) && (ax >= az);
    bool is_y = (!is_x) && (ay >= az);
    face = is_x ? (x > 0.f ? 0 : 1)
                : (is_y ? (y > 0.f ? 2 : 3) : (z > 0.f ? 4 : 5));
    float ma = fmaxf(is_x ? ax : (is_y ? ay : az), 1e-20f);
    float u = is_x ? (x > 0.f ? -z : z) : (is_y ? x : (z > 0.f ? x : -x));
    float v = is_y ? (y > 0.f ? z : -z) : -y;
    uo = u / ma;
    vo = v / ma;
}

__device__ __forceinline__ void bilinear3(const float* __restrict__ tex, int H, int W,
                                          int face, float fx, float fy,
                                          float& r, float& g, float& b) {
    float x0f = floorf(fx), y0f = floorf(fy);
    float tx = fx - x0f, ty = fy - y0f;
    int x0 = min(max((int)x0f, 0), W - 1);
    int x1 = min(x0 + 1, W - 1);
    int y0 = min(max((int)y0f, 0), H - 1);
    int y1 = min(y0 + 1, H - 1);
    const float* base = tex + (size_t)face * H * W * 3;
    const float* p00 = base + ((size_t)y0 * W + x0) * 3;
    const float* p01 = base + ((size_t)y0 * W + x1) * 3;
    const float* p10 = base + ((size_t)y1 * W + x0) * 3;
    const float* p11 = base + ((size_t)y1 * W + x1) * 3;
    float w00 = (1.f - tx) * (1.f - ty);
    float w01 = tx * (1.f - ty);
    float w10 = (1.f - tx) * ty;
    float w11 = tx * ty;
    r = p00[0] * w00 + p01[0] * w01 + p10[0] * w10 + p11[0] * w11;
    g = p00[1] * w00 + p01[1] * w01 + p10[1] * w10 + p11[1] * w11;
    b = p00[2] * w00 + p01[2] * w01 + p10[2] * w10 + p11[2] * w11;
}

__device__ __forceinline__ void sample_cubemap(const float* __restrict__ tex, int R,
                                               float dx, float dy, float dz,
                                               float& r, float& g, float& b) {
    int face; float u, v;
    cube_face_uv(dx, dy, dz, face, u, v);
    float fx = (u * 0.5f + 0.5f) * (float)R - 0.5f;
    float fy = (v * 0.5f + 0.5f) * (float)R - 0.5f;
    bilinear3(tex, R, R, face, fx, fy, r, g, b);
}

__device__ __forceinline__ void sample_lut2(const float* __restrict__ lut,
                                            float u, float v,
                                            float& o0, float& o1) {
    const int H = 256, W = 256;
    float fx = u * (float)W - 0.5f;
    float fy = v * (float)H - 0.5f;
    float x0f = floorf(fx), y0f = floorf(fy);
    float tx = fx - x0f, ty = fy - y0f;
    int x0 = min(max((int)x0f, 0), W - 1);
    int x1 = min(x0 + 1, W - 1);
    int y0 = min(max((int)y0f, 0), H - 1);
    int y1 = min(y0 + 1, H - 1);
    const float* p00 = lut + ((size_t)y0 * W + x0) * 2;
    const float* p01 = lut + ((size_t)y0 * W + x1) * 2;
    const float* p10 = lut + ((size_t)y1 * W + x0) * 2;
    const float* p11 = lut + ((size_t)y1 * W + x1) * 2;
    float w00 = (1.f - tx) * (1.f - ty);
    float w01 = tx * (1.f - ty);
    float w10 = (1.f - tx) * ty;
    float w11 = tx * ty;
    o0 = p00[0] * w00 + p01[0] * w01 + p10[0] * w10 + p11[0] * w11;
    o1 = p00[1] * w00 + p01[1] * w01 + p10[1] * w10 + p11[1] * w11;
}

__device__ __forceinline__ float rgb_to_srgb(float x) {
    // x already clipped to [0,1]
    return (x <= 0.0031308f) ? (12.92f * x)
                             : (1.055f * powf(fmaxf(x, 0.0031308f), 1.0f / 2.4f) - 0.055f);
}

__global__ __launch_bounds__(256)
void envlight_kernel(const float* __restrict__ view_dir,
                     const float* __restrict__ normal,
                     const float* __restrict__ kd,
                     const float* __restrict__ ks,
                     const float* __restrict__ reflect_occ,
                     const float* __restrict__ diffuse_map,
                     const float* __restrict__ s0, const float* __restrict__ s1,
                     const float* __restrict__ s2, const float* __restrict__ s3,
                     const float* __restrict__ s4, const float* __restrict__ s5,
                     const float* __restrict__ fg_lut,
                     float* __restrict__ out, int n)
{
    int i = blockIdx.x * blockDim.x + threadIdx.x;
    if (i >= n) return;

    float vx = view_dir[3 * i + 0], vy = view_dir[3 * i + 1], vz = view_dir[3 * i + 2];
    float nx = normal[3 * i + 0],  ny = normal[3 * i + 1],  nz = normal[3 * i + 2];
    float kdx = kd[3 * i + 0], kdy = kd[3 * i + 1], kdz = kd[3 * i + 2];
    float ks0 = ks[3 * i + 0], rough = ks[3 * i + 1], metallic = ks[3 * i + 2];
    float occ = reflect_occ[i];

    // spec_col / diff_col
    float scx = (1.f - metallic) * 0.04f + kdx * metallic;
    float scy = (1.f - metallic) * 0.04f + kdy * metallic;
    float scz = (1.f - metallic) * 0.04f + kdz * metallic;
    float dcx = kdx * (1.f - metallic);
    float dcy = kdy * (1.f - metallic);
    float dcz = kdz * (1.f - metallic);

    // reflect(view, normal), then safe-normalize
    float vdotn = vx * nx + vy * ny + vz * nz;
    float rx = 2.f * vdotn * nx - vx;
    float ry = 2.f * vdotn * ny - vy;
    float rz = 2.f * vdotn * nz - vz;
    float rlen2 = fmaxf(rx * rx + ry * ry + rz * rz, 1e-20f);
    float rinv = rsqrtf(rlen2);
    rx *= rinv; ry *= rinv; rz *= rinv;

    // diffuse cubemap sample at normal (16x16)
    float dfr, dfg, dfb;
    sample_cubemap(diffuse_map, 16, nx, ny, nz, dfr, dfg, dfb);
    dfr = fmaxf(dfr, 0.f); dfg = fmaxf(dfg, 0.f); dfb = fmaxf(dfb, 0.f);

    float shx = dfr * dcx * (1.f - ks0);
    float shy = dfg * dcy * (1.f - ks0);
    float shz = dfb * dcz * (1.f - ks0);

    // FG LUT
    float NdotV = fmaxf(vdotn, 1e-4f);
    float fg0, fg1;
    sample_lut2(fg_lut, NdotV, rough, fg0, fg1);

    // mip level from roughness
    const float MINR = 0.08f, MAXR = 0.5f;
    float lo = (fminf(fmaxf(rough, MINR), MAXR) - MINR) / (MAXR - MINR) * 4.0f;
    float hi = (fminf(fmaxf(rough, MAXR), 1.0f) - MAXR) / (1.0f - MAXR) + 4.0f;
    float lvl = (rough < MAXR) ? lo : hi;
    lvl = fminf(fmaxf(lvl, 0.f), 5.f);
    int l0 = (int)floorf(lvl);
    l0 = min(max(l0, 0), 5);
    int l1 = min(l0 + 1, 5);
    float f = lvl - (float)l0;

    // select mip pointers (per-lane cndmask chains; args are uniform)
    const float* tA = (l0 == 0) ? s0 : (l0 == 1) ? s1 : (l0 == 2) ? s2
                     : (l0 == 3) ? s3 : (l0 == 4) ? s4 : s5;
    int RA = 512 >> l0;
    const float* tB = (l1 == 1) ? s1 : (l1 == 2) ? s2 : (l1 == 3) ? s3
                     : (l1 == 4) ? s4 : s5;
    int RB = 512 >> l1;

    float ar, ag, ab, br, bg, bb;
    sample_cubemap(tA, RA, rx, ry, rz, ar, ag, ab);
    sample_cubemap(tB, RB, rx, ry, rz, br, bg, bb);
    float spr = ar * (1.f - f) + br * f;
    float spg = ag * (1.f - f) + bg * f;
    float spb = ab * (1.f - f) + bb * f;
    spr = fmaxf(spr, 0.f); spg = fmaxf(spg, 0.f); spb = fmaxf(spb, 0.f);

    float rfx = scx * fg0 + fg1;
    float rfy = scy * fg0 + fg1;
    float rfz = scz * fg0 + fg1;

    float om = 1.f - occ;
    shx += spr * rfx * om;
    shy += spg * rfy * om;
    shz += spb * rfz * om;

    shx = fminf(fmaxf(shx, 0.f), 1.f);
    shy = fminf(fmaxf(shy, 0.f), 1.f);
    shz = fminf(fmaxf(shz, 0.f), 1.f);

    out[3 * i + 0] = rgb_to_srgb(shx);
    out[3 * i + 1] = rgb_to_srgb(shy);
    out[3 * i + 2] = rgb_to_srgb(shz);
}

extern "C" void kernel_launch(void* const* d_in, const int* in_sizes, int n_in,
                              void* d_out, int out_size, void* d_ws, size_t ws_size,
                              hipStream_t stream) {
    const float* view_dir    = (const float*)d_in[0];
    const float* normal      = (const float*)d_in[1];
    const float* kd          = (const float*)d_in[2];
    const float* ks          = (const float*)d_in[3];
    const float* reflect_occ = (const float*)d_in[4];
    const float* diffuse_map = (const float*)d_in[5];
    const float* s0          = (const float*)d_in[6];
    const float* s1          = (const float*)d_in[7];
    const float* s2          = (const float*)d_in[8];
    const float* s3          = (const float*)d_in[9];
    const float* s4          = (const float*)d_in[10];
    const float* s5          = (const float*)d_in[11];
    const float* fg_lut      = (const float*)d_in[12];
    float* out = (float*)d_out;

    int n = in_sizes[0] / 3;
    int block = 256;
    int grid = (n + block - 1) / block;
    envlight_kernel<<<grid, block, 0, stream>>>(view_dir, normal, kd, ks, reflect_occ,
                                                diffuse_map, s0, s1, s2, s3, s4, s5,
                                                fg_lut, out, n);
}